// Round 5
// baseline (132.180 us; speedup 1.0000x reference)
//
#include <hip/hip_runtime.h>
#include <hip/hip_bf16.h>

typedef unsigned short ushort_t;
using ushort4v = __attribute__((ext_vector_type(4))) ushort_t;
using ushort8 = __attribute__((ext_vector_type(8))) ushort_t;
using short8  = __attribute__((ext_vector_type(8))) short;
using float4v = __attribute__((ext_vector_type(4))) float;

#define Bsz 256
#define Aattr 32
#define Ddim 2048

// Tiled operand layout ("fragment-ordered"): X_t[row/16][k/32][16][32] bf16.
// Element (row r, k c) lives at ((r>>4)*(Ddim/32) + (c>>5))*512 + (r&15)*32 + (c&31).
// A wave's MFMA frag load (lane = m16,quad reads [m16][quad*8+j]) is then ONE
// contiguous 1KB transaction instead of 16 lines scattered at 4KB stride.
#define KT (Ddim / 32)          // 64 k-tiles per 16-row tile
#define ROWTILE (KT * 512)      // elements per 16-row tile = 32768

__device__ __forceinline__ float bf2f(ushort_t u) {
    union { unsigned int i; float f; } c;
    c.i = ((unsigned int)u) << 16;
    return c.f;
}

__device__ __forceinline__ ushort_t f2bf(float f) {
    union { float f; unsigned int i; } c;
    c.f = f;
    unsigned int x = c.i;
    unsigned int r = (x + 0x7FFFu + ((x >> 16) & 1u)) >> 16;  // RNE
    return (ushort_t)r;
}

struct BfPair { ushort_t hi, lo; };
__device__ __forceinline__ BfPair split_bf16(float x) {
    BfPair p;
    p.hi = f2bf(x);
    p.lo = f2bf(x - bf2f(p.hi));
    return p;
}

__device__ __forceinline__ size_t tiled_off(int row, int k) {
    return (size_t)((row >> 4) * KT + (k >> 5)) * 512 + (row & 15) * 32 + (k & 31);
}

__device__ __forceinline__ float4 nt_load4(const float* p) {
    float4 v;
    v.x = __builtin_nontemporal_load(p + 0);
    v.y = __builtin_nontemporal_load(p + 1);
    v.z = __builtin_nontemporal_load(p + 2);
    v.w = __builtin_nontemporal_load(p + 3);
    return v;
}

// ---------------------------------------------------------------------------
// Kernel 1 (fused prep). ROUND-4/5 CHANGES (k_gemm2 untouched):
//  (1) transpose blocks remapped so the XCD that WRITES a WT row-range is the
//      XCD that READS it in k_gemm2 (reader XCD = n_tile>>2 = bx>>2; writer
//      XCD = q&7; choose bx = ((q&7)<<2)|((q>>3)&3)). Dirty WT lines in L2
//      become LOCAL hits instead of cross-XCD dirty snoops (~900+ cyc).
//  (2) S hi/lo stored NON-TEMPORAL (read by all 8 XCDs -> can't align; stream
//      them out clean so readers hit L3, no dirty-snoop).
//  (3) feat / W loaded NON-TEMPORAL (single-use streams) so they don't evict
//      the freshly written WT from the writer XCD's 4MB L2.
// ---------------------------------------------------------------------------
__global__ __launch_bounds__(256) void k_prep(
    const float* __restrict__ feat, const int* __restrict__ label,
    const float* __restrict__ W,
    ushort_t* __restrict__ s_hi, ushort_t* __restrict__ s_lo,
    ushort_t* __restrict__ WT_hi, ushort_t* __restrict__ WT_lo) {
    __shared__ float tile[64][65];   // wt path; reduce path reuses as int[]
    const int t = threadIdx.x;

    if (blockIdx.x < 512) {
        // ---- reduce path: b = id>>1, half = id&1 ----
        int* list = (int*)&tile[0][0];
        int* cntp = (int*)&tile[1][0];
        const int b    = blockIdx.x >> 1;
        const int half = blockIdx.x & 1;

        if (t < 64) {
            int lab = label[b * Aattr + (t & 31)];
            unsigned long long vote = __ballot(lab > 0);
            unsigned m32 = (unsigned)(vote & 0xFFFFFFFFull);
            if (t < 32) {
                if (lab > 0) {
                    int rank = __popc(m32 & ((1u << t) - 1u));
                    list[rank] = t;
                }
                if (t == 0) *cntp = __popc(m32);
            }
        }
        __syncthreads();

        const int n  = *cntp;
        const int d0 = half * 1024 + t * 4;
        const float* fb = feat + (size_t)b * (Aattr * Ddim) + d0;

        float a0 = 0.f, a1 = 0.f, a2 = 0.f, a3 = 0.f;
        int i = 0;
        for (; i + 4 <= n; i += 4) {
            const int j0 = list[i], j1 = list[i+1], j2 = list[i+2], j3 = list[i+3];
            float4 v0 = nt_load4(fb + j0 * Ddim);
            float4 v1 = nt_load4(fb + j1 * Ddim);
            float4 v2 = nt_load4(fb + j2 * Ddim);
            float4 v3 = nt_load4(fb + j3 * Ddim);
            a0 += v0.x + v1.x + v2.x + v3.x;
            a1 += v0.y + v1.y + v2.y + v3.y;
            a2 += v0.z + v1.z + v2.z + v3.z;
            a3 += v0.w + v1.w + v2.w + v3.w;
        }
        for (; i < n; ++i) {
            float4 v = nt_load4(fb + list[i] * Ddim);
            a0 += v.x; a1 += v.y; a2 += v.z; a3 += v.w;
        }

        ushort4v hi, lo;
        BfPair p0 = split_bf16(a0); hi[0] = p0.hi; lo[0] = p0.lo;
        BfPair p1 = split_bf16(a1); hi[1] = p1.hi; lo[1] = p1.lo;
        BfPair p2 = split_bf16(a2); hi[2] = p2.hi; lo[2] = p2.lo;
        BfPair p3 = split_bf16(a3); hi[3] = p3.hi; lo[3] = p3.lo;
        const size_t off = tiled_off(b, d0);   // d0..d0+3 stay in one 32-k tile
        __builtin_nontemporal_store(hi, (ushort4v*)(s_hi + off));
        __builtin_nontemporal_store(lo, (ushort4v*)(s_lo + off));
    } else {
        // ---- transpose+split path (writer-XCD == reader-XCD remap) ----
        const int q  = blockIdx.x - 512;
        const int bx = ((q & 7) << 2) | ((q >> 3) & 3);   // e-tile, XCD=q&7=bx>>2
        const int by = q >> 5;                            // d-tile

#pragma unroll
        for (int p = 0; p < 4; ++p) {
            const int row = p * 16 + (t >> 4);
            const int c   = (t & 15) * 4;
            float4 v = nt_load4(W + (size_t)(by * 64 + row) * Ddim + bx * 64 + c);
            tile[row][c + 0] = v.x;
            tile[row][c + 1] = v.y;
            tile[row][c + 2] = v.z;
            tile[row][c + 3] = v.w;
        }
        __syncthreads();
#pragma unroll
        for (int p = 0; p < 2; ++p) {
            const int er = p * 32 + (t >> 3);
            const int dc = (t & 7) * 8;
            ushort8 hi, lo;
#pragma unroll
            for (int j = 0; j < 8; ++j) {
                BfPair pr = split_bf16(tile[dc + j][er]);
                hi[j] = pr.hi; lo[j] = pr.lo;
            }
            // row e = bx*64+er, k = by*64+dc (8 consecutive k in one 32-tile)
            const size_t off = tiled_off(bx * 64 + er, by * 64 + dc);
            *(ushort8*)(WT_hi + off) = hi;   // normal store: dirty-local L2 hit
            *(ushort8*)(WT_lo + off) = lo;   // for the same-XCD gemm2 readers
        }
    }
}

// ---------------------------------------------------------------------------
// Kernel 2: fused GEMM + K-reduce + bias + tanh.  (byte-identical to round 3)
// Geometry: 256 blocks (1/CU) x 8 waves. Block tile 32(m)x64(n), K-split 8.
// Prefetch distance 2 (three rotating register buffer sets, static indexing).
// ---------------------------------------------------------------------------
__global__ __launch_bounds__(512, 2) void k_gemm2(
    const ushort_t* __restrict__ S_hi, const ushort_t* __restrict__ S_lo,
    const ushort_t* __restrict__ WT_hi, const ushort_t* __restrict__ WT_lo,
    const float* __restrict__ bias, float* __restrict__ out) {
    __shared__ float red[8][32 * 68];   // 69632 B

    const int g      = blockIdx.x;
    const int q      = g >> 3;
    const int n_tile = (g & 7) * 4 + (q & 3);   // [0,32)
    const int m_tile = q >> 2;                  // [0,8)
    const int m0     = m_tile * 32;
    const int n0     = n_tile * 64;

    const int t    = threadIdx.x;
    const int w    = t >> 6;          // wave id 0..7 = K-chunk
    const int l    = t & 63;
    const int quad = l >> 4;
    const int m16  = l & 15;

    float4v acc[2][4];
#pragma unroll
    for (int i = 0; i < 2; ++i)
#pragma unroll
        for (int j = 0; j < 4; ++j) acc[i][j] = {0.f, 0.f, 0.f, 0.f};

    // Wave base pointers into tiled operands. kt0 = w*8 (8 k-tiles per wave).
    const int lane_off = m16 * 32 + quad * 8;
    const size_t abase = (size_t)((m0 >> 4) * KT + w * 8) * 512 + lane_off;
    const size_t bbase = (size_t)((n0 >> 4) * KT + w * 8) * 512 + lane_off;
    const ushort_t* pAh = S_hi + abase;
    const ushort_t* pAl = S_lo + abase;
    const ushort_t* pBh = WT_hi + bbase;
    const ushort_t* pBl = WT_lo + bbase;

    short8 Ah_[3][2], Al_[3][2], Bh_[3][4], Bl_[3][4];

#define LOADSET(buf, it)                                                     \
    do {                                                                     \
        Ah_[buf][0] = *(const short8*)(pAh + (it) * 512);                    \
        Ah_[buf][1] = *(const short8*)(pAh + ROWTILE + (it) * 512);          \
        Al_[buf][0] = *(const short8*)(pAl + (it) * 512);                    \
        Al_[buf][1] = *(const short8*)(pAl + ROWTILE + (it) * 512);          \
        _Pragma("unroll")                                                    \
        for (int i_ = 0; i_ < 4; ++i_) {                                     \
            Bh_[buf][i_] = *(const short8*)(pBh + i_ * ROWTILE + (it) * 512);\
            Bl_[buf][i_] = *(const short8*)(pBl + i_ * ROWTILE + (it) * 512);\
        }                                                                    \
    } while (0)

    LOADSET(0, 0);
    LOADSET(1, 1);
#pragma unroll
    for (int it = 0; it < 8; ++it) {
        const int cur = it % 3;
        if (it < 6) {
            const int nxt = (it + 2) % 3;
            LOADSET(nxt, it + 2);
        }
#pragma unroll
        for (int ni = 0; ni < 4; ++ni) {
            acc[0][ni] = __builtin_amdgcn_mfma_f32_16x16x32_bf16(Ah_[cur][0], Bh_[cur][ni], acc[0][ni], 0, 0, 0);
            acc[0][ni] = __builtin_amdgcn_mfma_f32_16x16x32_bf16(Ah_[cur][0], Bl_[cur][ni], acc[0][ni], 0, 0, 0);
            acc[0][ni] = __builtin_amdgcn_mfma_f32_16x16x32_bf16(Al_[cur][0], Bh_[cur][ni], acc[0][ni], 0, 0, 0);
            acc[1][ni] = __builtin_amdgcn_mfma_f32_16x16x32_bf16(Ah_[cur][1], Bh_[cur][ni], acc[1][ni], 0, 0, 0);
            acc[1][ni] = __builtin_amdgcn_mfma_f32_16x16x32_bf16(Ah_[cur][1], Bl_[cur][ni], acc[1][ni], 0, 0, 0);
            acc[1][ni] = __builtin_amdgcn_mfma_f32_16x16x32_bf16(Al_[cur][1], Bh_[cur][ni], acc[1][ni], 0, 0, 0);
        }
    }
#undef LOADSET

    // dump wave tiles to LDS (C/D layout: col(n)=lane&15, row(m)=quad*4+reg)
#pragma unroll
    for (int mi = 0; mi < 2; ++mi) {
#pragma unroll
        for (int ni = 0; ni < 4; ++ni) {
#pragma unroll
            for (int rr = 0; rr < 4; ++rr) {
                red[w][(mi * 16 + quad * 4 + rr) * 68 + ni * 16 + m16] = acc[mi][ni][rr];
            }
        }
    }
    __syncthreads();

    // reduce the 8 K-chunk waves + bias + tanh.
    // thread t -> m_l = t>>4 (0..31), n_l = (t&15)*4
    const int m_l  = t >> 4;
    const int n_l  = (t & 15) * 4;
    const int base = m_l * 68 + n_l;
    float s0 = 0.f, s1 = 0.f, s2 = 0.f, s3 = 0.f;
#pragma unroll
    for (int ww = 0; ww < 8; ++ww) {
        float4 v = *(const float4*)&red[ww][base];
        s0 += v.x; s1 += v.y; s2 += v.z; s3 += v.w;
    }
    float4 b0 = *(const float4*)(bias + n0 + n_l);
    float4 o0;
    o0.x = tanhf(s0 + b0.x);
    o0.y = tanhf(s1 + b0.y);
    o0.z = tanhf(s2 + b0.z);
    o0.w = tanhf(s3 + b0.w);
    *(float4*)(out + (size_t)(m0 + m_l) * Ddim + n0 + n_l) = o0;
}

extern "C" void kernel_launch(void* const* d_in, const int* in_sizes, int n_in,
                              void* d_out, int out_size, void* d_ws, size_t ws_size,
                              hipStream_t stream) {
    // inputs (fp32 unless noted): x (dead for returned row), feat[256*32*2048],
    // label[256*32] (int32), W[2048*2048], b[2048]
    const float* feat  = (const float*)d_in[1];
    const int*   label = (const int*)d_in[2];
    const float* W     = (const float*)d_in[3];
    const float* bias  = (const float*)d_in[4];
    float*       out   = (float*)d_out;

    char* ws = (char*)d_ws;
    ushort_t* s_hi  = (ushort_t*)ws;                 // 1 MB
    ushort_t* s_lo  = (ushort_t*)(ws + (1u << 20));  // 1 MB
    ushort_t* WT_hi = (ushort_t*)(ws + (2u << 20));  // 8 MB
    ushort_t* WT_lo = (ushort_t*)(ws + (10u << 20)); // 8 MB

    k_prep<<<dim3(1536), dim3(256), 0, stream>>>(feat, label, W, s_hi, s_lo, WT_hi, WT_lo);
    k_gemm2<<<dim3(256), dim3(512), 0, stream>>>(s_hi, s_lo, WT_hi, WT_lo, bias, out);
}

// Round 6
// 126.770 us; speedup vs baseline: 1.0427x; 1.0427x over previous
//
#include <hip/hip_runtime.h>
#include <hip/hip_bf16.h>

typedef unsigned short ushort_t;
using ushort4v = __attribute__((ext_vector_type(4))) ushort_t;
using ushort8 = __attribute__((ext_vector_type(8))) ushort_t;
using short8  = __attribute__((ext_vector_type(8))) short;
using float4v = __attribute__((ext_vector_type(4))) float;

#define Bsz 256
#define Aattr 32
#define Ddim 2048

// Tiled operand layout ("fragment-ordered"): X_t[row/16][k/32][16][32] bf16.
// Element (row r, k c) lives at ((r>>4)*(Ddim/32) + (c>>5))*512 + (r&15)*32 + (c&31).
// A wave's MFMA frag load (lane = m16,quad reads [m16][quad*8+j]) is then ONE
// contiguous 1KB transaction instead of 16 lines scattered at 4KB stride.
#define KT (Ddim / 32)          // 64 k-tiles per 16-row tile
#define ROWTILE (KT * 512)      // elements per 16-row tile = 32768

__device__ __forceinline__ float bf2f(ushort_t u) {
    union { unsigned int i; float f; } c;
    c.i = ((unsigned int)u) << 16;
    return c.f;
}

__device__ __forceinline__ ushort_t f2bf(float f) {
    union { float f; unsigned int i; } c;
    c.f = f;
    unsigned int x = c.i;
    unsigned int r = (x + 0x7FFFu + ((x >> 16) & 1u)) >> 16;  // RNE
    return (ushort_t)r;
}

struct BfPair { ushort_t hi, lo; };
__device__ __forceinline__ BfPair split_bf16(float x) {
    BfPair p;
    p.hi = f2bf(x);
    p.lo = f2bf(x - bf2f(p.hi));
    return p;
}

__device__ __forceinline__ size_t tiled_off(int row, int k) {
    return (size_t)((row >> 4) * KT + (k >> 5)) * 512 + (row & 15) * 32 + (k & 31);
}

// ---------------------------------------------------------------------------
// Kernel 1 (fused prep): reverted byte-identical to round 3 (the 127.4 us
// reference). R5's nt_load4 de-vectorized the hot loads (4x dword vs dwordx4)
// and regressed the total by ~5 us; NT hints + XCD remap are also dropped to
// keep this round single-lever.
// ---------------------------------------------------------------------------
__global__ __launch_bounds__(256) void k_prep(
    const float* __restrict__ feat, const int* __restrict__ label,
    const float* __restrict__ W,
    ushort_t* __restrict__ s_hi, ushort_t* __restrict__ s_lo,
    ushort_t* __restrict__ WT_hi, ushort_t* __restrict__ WT_lo) {
    __shared__ float tile[64][65];   // wt path; reduce path reuses as int[]
    const int t = threadIdx.x;

    if (blockIdx.x < 512) {
        // ---- reduce path: b = id>>1, half = id&1 ----
        int* list = (int*)&tile[0][0];
        int* cntp = (int*)&tile[1][0];
        const int b    = blockIdx.x >> 1;
        const int half = blockIdx.x & 1;

        if (t < 64) {
            int lab = label[b * Aattr + (t & 31)];
            unsigned long long vote = __ballot(lab > 0);
            unsigned m32 = (unsigned)(vote & 0xFFFFFFFFull);
            if (t < 32) {
                if (lab > 0) {
                    int rank = __popc(m32 & ((1u << t) - 1u));
                    list[rank] = t;
                }
                if (t == 0) *cntp = __popc(m32);
            }
        }
        __syncthreads();

        const int n  = *cntp;
        const int d0 = half * 1024 + t * 4;
        const float* fb = feat + (size_t)b * (Aattr * Ddim) + d0;

        float a0 = 0.f, a1 = 0.f, a2 = 0.f, a3 = 0.f;
        int i = 0;
        for (; i + 4 <= n; i += 4) {
            const int j0 = list[i], j1 = list[i+1], j2 = list[i+2], j3 = list[i+3];
            float4 v0 = *(const float4*)(fb + j0 * Ddim);
            float4 v1 = *(const float4*)(fb + j1 * Ddim);
            float4 v2 = *(const float4*)(fb + j2 * Ddim);
            float4 v3 = *(const float4*)(fb + j3 * Ddim);
            a0 += v0.x + v1.x + v2.x + v3.x;
            a1 += v0.y + v1.y + v2.y + v3.y;
            a2 += v0.z + v1.z + v2.z + v3.z;
            a3 += v0.w + v1.w + v2.w + v3.w;
        }
        for (; i < n; ++i) {
            float4 v = *(const float4*)(fb + list[i] * Ddim);
            a0 += v.x; a1 += v.y; a2 += v.z; a3 += v.w;
        }

        ushort4v hi, lo;
        BfPair p0 = split_bf16(a0); hi[0] = p0.hi; lo[0] = p0.lo;
        BfPair p1 = split_bf16(a1); hi[1] = p1.hi; lo[1] = p1.lo;
        BfPair p2 = split_bf16(a2); hi[2] = p2.hi; lo[2] = p2.lo;
        BfPair p3 = split_bf16(a3); hi[3] = p3.hi; lo[3] = p3.lo;
        const size_t off = tiled_off(b, d0);   // d0..d0+3 stay in one 32-k tile
        *(ushort4v*)(s_hi + off) = hi;
        *(ushort4v*)(s_lo + off) = lo;
    } else {
        // ---- transpose+split path ----
        const int q  = blockIdx.x - 512;
        const int bx = q & 31;        // e-tile
        const int by = q >> 5;        // d-tile

#pragma unroll
        for (int p = 0; p < 4; ++p) {
            const int row = p * 16 + (t >> 4);
            const int c   = (t & 15) * 4;
            float4 v = *(const float4*)(W + (size_t)(by * 64 + row) * Ddim + bx * 64 + c);
            tile[row][c + 0] = v.x;
            tile[row][c + 1] = v.y;
            tile[row][c + 2] = v.z;
            tile[row][c + 3] = v.w;
        }
        __syncthreads();
#pragma unroll
        for (int p = 0; p < 2; ++p) {
            const int er = p * 32 + (t >> 3);
            const int dc = (t & 7) * 8;
            ushort8 hi, lo;
#pragma unroll
            for (int j = 0; j < 8; ++j) {
                BfPair pr = split_bf16(tile[dc + j][er]);
                hi[j] = pr.hi; lo[j] = pr.lo;
            }
            // row e = bx*64+er, k = by*64+dc (8 consecutive k in one 32-tile)
            const size_t off = tiled_off(bx * 64 + er, by * 64 + dc);
            *(ushort8*)(WT_hi + off) = hi;
            *(ushort8*)(WT_lo + off) = lo;
        }
    }
}

// ---------------------------------------------------------------------------
// Kernel 2: fused GEMM + K-reduce + bias + tanh.
// Geometry as round 3: 256 blocks (1/CU) x 8 waves, tile 32(m)x64(n), K-split 8,
// prefetch distance 2 (three rotating register buffer sets).
// ROUND-6 CHANGE: __builtin_amdgcn_sched_barrier(0) between the prefetch
// LOADSET(it+2) and the MFMA cluster of iteration it. Evidence the pipeline
// never materialized: R2 counters showed k_gemm2 VGPR_Count=64 — 3 buffer
// sets (144 VGPR) + 32 acc cannot fit in 64, so the compiler had sunk every
// load to just-before-use, serializing a full memory latency per iteration
// (19 us = 5700 cyc/iter vs 240-cyc intended cover). The fence pins issue
// order: loads of it+2 must issue before MFMAs of it -> counted vmcnt,
// ~2 iterations of in-flight cover, ~196 VGPR (no spill, 2 waves/SIMD).
// ---------------------------------------------------------------------------
__global__ __launch_bounds__(512, 2) void k_gemm2(
    const ushort_t* __restrict__ S_hi, const ushort_t* __restrict__ S_lo,
    const ushort_t* __restrict__ WT_hi, const ushort_t* __restrict__ WT_lo,
    const float* __restrict__ bias, float* __restrict__ out) {
    __shared__ float red[8][32 * 68];   // 69632 B

    const int g      = blockIdx.x;
    const int q      = g >> 3;
    const int n_tile = (g & 7) * 4 + (q & 3);   // [0,32)
    const int m_tile = q >> 2;                  // [0,8)
    const int m0     = m_tile * 32;
    const int n0     = n_tile * 64;

    const int t    = threadIdx.x;
    const int w    = t >> 6;          // wave id 0..7 = K-chunk
    const int l    = t & 63;
    const int quad = l >> 4;
    const int m16  = l & 15;

    float4v acc[2][4];
#pragma unroll
    for (int i = 0; i < 2; ++i)
#pragma unroll
        for (int j = 0; j < 4; ++j) acc[i][j] = {0.f, 0.f, 0.f, 0.f};

    // Wave base pointers into tiled operands. kt0 = w*8 (8 k-tiles per wave).
    const int lane_off = m16 * 32 + quad * 8;
    const size_t abase = (size_t)((m0 >> 4) * KT + w * 8) * 512 + lane_off;
    const size_t bbase = (size_t)((n0 >> 4) * KT + w * 8) * 512 + lane_off;
    const ushort_t* pAh = S_hi + abase;
    const ushort_t* pAl = S_lo + abase;
    const ushort_t* pBh = WT_hi + bbase;
    const ushort_t* pBl = WT_lo + bbase;

    short8 Ah_[3][2], Al_[3][2], Bh_[3][4], Bl_[3][4];

#define LOADSET(buf, it)                                                     \
    do {                                                                     \
        Ah_[buf][0] = *(const short8*)(pAh + (it) * 512);                    \
        Ah_[buf][1] = *(const short8*)(pAh + ROWTILE + (it) * 512);          \
        Al_[buf][0] = *(const short8*)(pAl + (it) * 512);                    \
        Al_[buf][1] = *(const short8*)(pAl + ROWTILE + (it) * 512);          \
        _Pragma("unroll")                                                    \
        for (int i_ = 0; i_ < 4; ++i_) {                                     \
            Bh_[buf][i_] = *(const short8*)(pBh + i_ * ROWTILE + (it) * 512);\
            Bl_[buf][i_] = *(const short8*)(pBl + i_ * ROWTILE + (it) * 512);\
        }                                                                    \
    } while (0)

    LOADSET(0, 0);
    LOADSET(1, 1);
#pragma unroll
    for (int it = 0; it < 8; ++it) {
        const int cur = it % 3;
        if (it < 6) {
            const int nxt = (it + 2) % 3;
            LOADSET(nxt, it + 2);
        }
        // Pin the pipeline: nothing (esp. the prefetch loads above) may be
        // moved below this point, and the MFMAs may not be hoisted above it.
        __builtin_amdgcn_sched_barrier(0);
#pragma unroll
        for (int ni = 0; ni < 4; ++ni) {
            acc[0][ni] = __builtin_amdgcn_mfma_f32_16x16x32_bf16(Ah_[cur][0], Bh_[cur][ni], acc[0][ni], 0, 0, 0);
            acc[0][ni] = __builtin_amdgcn_mfma_f32_16x16x32_bf16(Ah_[cur][0], Bl_[cur][ni], acc[0][ni], 0, 0, 0);
            acc[0][ni] = __builtin_amdgcn_mfma_f32_16x16x32_bf16(Al_[cur][0], Bh_[cur][ni], acc[0][ni], 0, 0, 0);
            acc[1][ni] = __builtin_amdgcn_mfma_f32_16x16x32_bf16(Ah_[cur][1], Bh_[cur][ni], acc[1][ni], 0, 0, 0);
            acc[1][ni] = __builtin_amdgcn_mfma_f32_16x16x32_bf16(Ah_[cur][1], Bl_[cur][ni], acc[1][ni], 0, 0, 0);
            acc[1][ni] = __builtin_amdgcn_mfma_f32_16x16x32_bf16(Al_[cur][1], Bh_[cur][ni], acc[1][ni], 0, 0, 0);
        }
    }
#undef LOADSET

    // dump wave tiles to LDS (C/D layout: col(n)=lane&15, row(m)=quad*4+reg)
#pragma unroll
    for (int mi = 0; mi < 2; ++mi) {
#pragma unroll
        for (int ni = 0; ni < 4; ++ni) {
#pragma unroll
            for (int rr = 0; rr < 4; ++rr) {
                red[w][(mi * 16 + quad * 4 + rr) * 68 + ni * 16 + m16] = acc[mi][ni][rr];
            }
        }
    }
    __syncthreads();

    // reduce the 8 K-chunk waves + bias + tanh.
    // thread t -> m_l = t>>4 (0..31), n_l = (t&15)*4
    const int m_l  = t >> 4;
    const int n_l  = (t & 15) * 4;
    const int base = m_l * 68 + n_l;
    float s0 = 0.f, s1 = 0.f, s2 = 0.f, s3 = 0.f;
#pragma unroll
    for (int ww = 0; ww < 8; ++ww) {
        float4 v = *(const float4*)&red[ww][base];
        s0 += v.x; s1 += v.y; s2 += v.z; s3 += v.w;
    }
    float4 b0 = *(const float4*)(bias + n0 + n_l);
    float4 o0;
    o0.x = tanhf(s0 + b0.x);
    o0.y = tanhf(s1 + b0.y);
    o0.z = tanhf(s2 + b0.z);
    o0.w = tanhf(s3 + b0.w);
    *(float4*)(out + (size_t)(m0 + m_l) * Ddim + n0 + n_l) = o0;
}

extern "C" void kernel_launch(void* const* d_in, const int* in_sizes, int n_in,
                              void* d_out, int out_size, void* d_ws, size_t ws_size,
                              hipStream_t stream) {
    // inputs (fp32 unless noted): x (dead for returned row), feat[256*32*2048],
    // label[256*32] (int32), W[2048*2048], b[2048]
    const float* feat  = (const float*)d_in[1];
    const int*   label = (const int*)d_in[2];
    const float* W     = (const float*)d_in[3];
    const float* bias  = (const float*)d_in[4];
    float*       out   = (float*)d_out;

    char* ws = (char*)d_ws;
    ushort_t* s_hi  = (ushort_t*)ws;                 // 1 MB
    ushort_t* s_lo  = (ushort_t*)(ws + (1u << 20));  // 1 MB
    ushort_t* WT_hi = (ushort_t*)(ws + (2u << 20));  // 8 MB
    ushort_t* WT_lo = (ushort_t*)(ws + (10u << 20)); // 8 MB

    k_prep<<<dim3(1536), dim3(256), 0, stream>>>(feat, label, W, s_hi, s_lo, WT_hi, WT_lo);
    k_gemm2<<<dim3(256), dim3(512), 0, stream>>>(s_hi, s_lo, WT_hi, WT_lo, bias, out);
}